// Round 4
// baseline (581.748 us; speedup 1.0000x reference)
//
#include <hip/hip_runtime.h>
#include <math.h>

// Problem constants
#define B_    1024
#define D_    512
#define V_    100000
#define NP_   100096            // padded V (782 tiles * 128)
#define NT_   782
#define EPS_  1e-7f
#define COSM  0.9210609940028851f   // cos(0.4)
#define SINM  0.3894183423086505f   // sin(0.4)

typedef __bf16 bf16x8 __attribute__((ext_vector_type(8)));
typedef float  f32x4  __attribute__((ext_vector_type(4)));

struct alignas(16) US8 { unsigned short h[8]; };

// round-to-nearest-even float -> bf16 bits (inputs finite)
__device__ __forceinline__ unsigned short f2bf(float f) {
  union { float f; unsigned u; } a; a.f = f;
  unsigned u = a.u;
  u += 0x7FFFu + ((u >> 16) & 1u);
  return (unsigned short)(u >> 16);
}

__device__ __forceinline__ void async_copy16(void* lds, const void* g) {
  __builtin_amdgcn_global_load_lds(
      (const __attribute__((address_space(1))) void*)g,
      (__attribute__((address_space(3))) void*)lds, 16, 0, 0);
}

// ---------------------------------------------------------------------------
// Kernel 1: L2-normalize rows of x -> bf16; zero S.
// grid 256 x block 256 (4 waves = 4 rows per block)
// ---------------------------------------------------------------------------
__global__ void x_prep(const float* __restrict__ x,
                       unsigned short* __restrict__ xb,
                       float* __restrict__ S) {
  int t = threadIdx.x;
  int lane = t & 63, wave = t >> 6;
  int row = blockIdx.x * 4 + wave;
  const float* xr = x + (size_t)row * D_;
  f32x4 a = *(const f32x4*)(xr + lane * 8);
  f32x4 b = *(const f32x4*)(xr + lane * 8 + 4);
  float ss = a[0]*a[0] + a[1]*a[1] + a[2]*a[2] + a[3]*a[3]
           + b[0]*b[0] + b[1]*b[1] + b[2]*b[2] + b[3]*b[3];
#pragma unroll
  for (int off = 32; off > 0; off >>= 1) ss += __shfl_xor(ss, off, 64);
  float inv = 1.0f / fmaxf(sqrtf(ss), 1e-12f);
  US8 pk;
#pragma unroll
  for (int j = 0; j < 4; ++j) pk.h[j]     = f2bf(a[j] * inv);
#pragma unroll
  for (int j = 0; j < 4; ++j) pk.h[4 + j] = f2bf(b[j] * inv);
  *(US8*)(xb + (size_t)row * D_ + lane * 8) = pk;
  if (lane == 0) S[row] = 0.0f;
}

// ---------------------------------------------------------------------------
// Kernel 1b (v4): w fp32 [D][V] -> bf16 transposed wbT [NP][D].
// WPC=128 cols/block so each w-row read is 512B/block (2x DRAM page
// locality vs v3's 256B) and 32 loads in flight/thread. K in halves of 256.
// Thread = col-quad (t&31) x row-group (t>>5); assembles US8 of 8
// consecutive rows in registers; LDS slot = kchunk ^ colquad (full 32-slot
// spread both phases). Writes stay 512B-per-column. 68KB LDS -> 2 blk/CU.
// grid 782 x block 256.
// ---------------------------------------------------------------------------
#define WPC 128
#define KH  256

__global__ __launch_bounds__(256) void w_prep(const float* __restrict__ w,
                                              unsigned short* __restrict__ wbT,
                                              float* __restrict__ wssq) {
  __shared__ US8  T16[WPC][32];   // 64 KB (128 cols x 32 chunks of 16B)
  __shared__ float sq[8][WPC];    // 4 KB
  int t = threadIdx.x;
  int c0 = blockIdx.x * WPC;
  int q32 = t & 31;               // column quad 0..31 (cols q32*4..+3)
  int rg = t >> 5;                // row group 0..7
  int colv = q32 * 4;
  int lane = t & 63, wave = t >> 6;
  bool vok = (c0 + colv + 3) < V_;   // all-or-nothing (V_ % 4 == 0)
  float ssq[4] = {0.0f, 0.0f, 0.0f, 0.0f};

  for (int h = 0; h < 2; ++h) {
    // ---- phase 1: 512B-per-row coalesced reads, reg-assemble, b128 write
#pragma unroll
    for (int m = 0; m < 4; ++m) {
      int kchunk = rg + m * 8;                 // 0..31 within half
      int rowb = h * KH + kchunk * 8;
      US8 pk[4] = {};
      if (vok) {
#pragma unroll
        for (int i = 0; i < 8; ++i) {
          f32x4 v = *(const f32x4*)(w + (size_t)(rowb + i) * V_ + c0 + colv);
#pragma unroll
          for (int cc = 0; cc < 4; ++cc) {
            ssq[cc] += v[cc] * v[cc];
            pk[cc].h[i] = f2bf(v[cc]);
          }
        }
      }
#pragma unroll
      for (int cc = 0; cc < 4; ++cc)
        T16[colv + cc][kchunk ^ q32] = pk[cc];    // col>>2 == q32
    }
    __syncthreads();
    // ---- phase 2: conflict-free LDS read, coalesced 512B-per-col stores
#pragma unroll
    for (int ci = 0; ci < 16; ++ci) {
      int col = wave * 32 + ci * 2 + (lane >> 5);
      int kc = lane & 31;
      US8 pk = T16[col][kc ^ (col >> 2)];
      *(US8*)(wbT + (size_t)(c0 + col) * D_ + h * KH + kc * 8) = pk;
    }
    __syncthreads();   // T16 reused next half
  }

  // ---- column sum-of-squares: block-local reduce, direct store
#pragma unroll
  for (int cc = 0; cc < 4; ++cc) sq[rg][colv + cc] = ssq[cc];
  __syncthreads();
  if (t < WPC && (c0 + t) < V_) {
    float tot = 0.0f;
#pragma unroll
    for (int p = 0; p < 8; ++p) tot += sq[p][t];
    wssq[c0 + t] = tot;
  }
}

// ---------------------------------------------------------------------------
// Kernel 2 (v4): BM=256 x BN=128 bf16 MFMA GEMM, 512 threads / 8 waves.
// T4 counted-vmcnt 2-deep pipeline with raw s_barrier (NOT __syncthreads,
// which drains vmcnt(0) and defeats the pipeline — the m97 ceiling):
//   prologue: stage t0,t1 (12 loads); vmcnt(6); barrier
//   iter t:   compute buf[t&1]; barrier; stage t+2 into buf[t&1];
//             vmcnt(6) [t+1's loads landed, t+2's stay in flight]; barrier
// LDS 2x48KB = 96KB -> 1 block/CU; intra-block overlap replaces TLP.
// Labels read straight from global in epilogue (keeps manual vmcnt exact).
// grid 3136 x block 512.
// ---------------------------------------------------------------------------
#define BM 256
#define BN 128
#define BK 64
#define NKT (D_ / BK)

__global__ __launch_bounds__(512) void gemm_fused_dma(
    const unsigned short* __restrict__ xb,
    const unsigned short* __restrict__ wbT,
    const float* __restrict__ wssq,
    const int* __restrict__ labels,
    float* __restrict__ S, float* __restrict__ Lb) {
  int bid = blockIdx.x;
  int xcd = bid & 7;
  int slot = bid >> 3;          // 0..391
  int tm = slot & 3;
  int tn = xcd * 98 + (slot >> 2);
  if (tn >= NT_) return;
  int m0 = tm * BM, n0 = tn * BN;

  // LDS slot p (16B chunks) holds (m = p>>3, kc = (p&7) ^ (m&7))
  __shared__ unsigned short Ab[2 * BM * BK];  // 64 KB
  __shared__ unsigned short Bb[2 * BN * BK];  // 32 KB
  int t = threadIdx.x;
  int lane = t & 63;
  int q = lane >> 4, l15 = lane & 15;
  int wave = t >> 6;                      // 0..7
  int wm = (wave & 3) * 64, wn = (wave >> 2) * 64;
  f32x4 acc[4][4] = {};

  // ---- staging addresses: pre-swizzled global src, linear LDS dest ----
  const unsigned short* gA[4]; int oA[4];
  const unsigned short* gB[2]; int oB[2];
#pragma unroll
  for (int j = 0; j < 4; ++j) {
    int p = t + 512 * j;                  // 0..2047
    int m = p >> 3;
    int kc = (p & 7) ^ (m & 7);
    gA[j] = xb + (size_t)(m0 + m) * D_ + kc * 8;
    oA[j] = p * 8;
  }
#pragma unroll
  for (int j = 0; j < 2; ++j) {
    int p = t + 512 * j;                  // 0..1023
    int m = p >> 3;
    int kc = (p & 7) ^ (m & 7);
    gB[j] = wbT + (size_t)(n0 + m) * D_ + kc * 8;   // wbT is [col][K]
    oB[j] = p * 8;
  }

  // ---- prologue: stage tiles 0 and 1 (6 loads each/thread) ----
#pragma unroll
  for (int j = 0; j < 4; ++j) async_copy16(Ab + oA[j], gA[j]);
#pragma unroll
  for (int j = 0; j < 2; ++j) async_copy16(Bb + oB[j], gB[j]);
#pragma unroll
  for (int j = 0; j < 4; ++j) async_copy16(Ab + BM * BK + oA[j], gA[j] + BK);
#pragma unroll
  for (int j = 0; j < 2; ++j) async_copy16(Bb + BN * BK + oB[j], gB[j] + BK);
  asm volatile("s_waitcnt vmcnt(6)" ::: "memory");   // tile 0 landed
  __builtin_amdgcn_sched_barrier(0);
  __builtin_amdgcn_s_barrier();
  __builtin_amdgcn_sched_barrier(0);

  int h = l15 & 7;
  for (int tt = 0; tt < NKT; ++tt) {
    int b = tt & 1;
    const unsigned short* Ac = Ab + b * (BM * BK);
    const unsigned short* Bc = Bb + b * (BN * BK);
#pragma unroll
    for (int s = 0; s < 2; ++s) {
      int kx = s * 4 + q;
      bf16x8 af[4], bfr[4];
#pragma unroll
      for (int ri = 0; ri < 4; ++ri) {
        int row_ = wm + ri * 16 + l15;
        af[ri] = *(const bf16x8*)&Ac[(row_ * 8 + (kx ^ h)) * 8];
      }
#pragma unroll
      for (int ci = 0; ci < 4; ++ci) {
        int row_ = wn + ci * 16 + l15;
        bfr[ci] = *(const bf16x8*)&Bc[(row_ * 8 + (kx ^ h)) * 8];
      }
#pragma unroll
      for (int ri = 0; ri < 4; ++ri)
#pragma unroll
        for (int ci = 0; ci < 4; ++ci)
          acc[ri][ci] = __builtin_amdgcn_mfma_f32_16x16x32_bf16(
              af[ri], bfr[ci], acc[ri][ci], 0, 0, 0);
    }
    // all waves done ds_reading buf b before its DMA overwrite is issued
    __builtin_amdgcn_sched_barrier(0);
    __builtin_amdgcn_s_barrier();
    __builtin_amdgcn_sched_barrier(0);
    if (tt + 2 < NKT) {
      int kk = (tt + 2) * BK;
#pragma unroll
      for (int j = 0; j < 4; ++j)
        async_copy16(Ab + b * (BM * BK) + oA[j], gA[j] + kk);
#pragma unroll
      for (int j = 0; j < 2; ++j)
        async_copy16(Bb + b * (BN * BK) + oB[j], gB[j] + kk);
      asm volatile("s_waitcnt vmcnt(6)" ::: "memory");  // t+1 landed
    } else {
      asm volatile("s_waitcnt vmcnt(0)" ::: "memory");  // drain tail
    }
    __builtin_amdgcn_sched_barrier(0);
    __builtin_amdgcn_s_barrier();
    __builtin_amdgcn_sched_barrier(0);
  }

  // ---- epilogue: C/D layout col = lane&15 (n side), row = q*4 + reg ----
  float iw[4]; int vcol[4];
#pragma unroll
  for (int ci = 0; ci < 4; ++ci) {
    int nl = wn + ci * 16 + l15;
    vcol[ci] = n0 + nl;
    iw[ci] = (vcol[ci] < V_) ? 1.0f / fmaxf(sqrtf(wssq[vcol[ci]]), 1e-12f)
                             : 0.0f;
  }
#pragma unroll
  for (int ri = 0; ri < 4; ++ri) {
#pragma unroll
    for (int reg = 0; reg < 4; ++reg) {
      int ml = wm + ri * 16 + q * 4 + reg;
      int r = m0 + ml;
      int lab = labels[r];
      float s = 0.0f;
#pragma unroll
      for (int ci = 0; ci < 4; ++ci) {
        float cv = acc[ri][ci][reg] * iw[ci];
        cv = fminf(fmaxf(cv, -1.0f + EPS_), 1.0f - EPS_);
        float logit = cv;
        if (vcol[ci] == lab) {
          logit = cv * COSM - sqrtf(fmaxf(1.0f - cv * cv, 0.0f)) * SINM;
          Lb[r] = logit;               // unique writer across grid
        }
        s += (vcol[ci] < V_) ? __expf(logit) : 0.0f;
      }
      s += __shfl_xor(s, 1, 64);
      s += __shfl_xor(s, 2, 64);
      s += __shfl_xor(s, 4, 64);
      s += __shfl_xor(s, 8, 64);
      if (l15 == 0) atomicAdd(&S[r], s);
    }
  }
}

// ---------------------------------------------------------------------------
// Kernel 2 FALLBACK (verbatim R0 best, own 128x128x64 constants): inline
// fp32->bf16 B-path. Used only if the workspace is too small for wbT.
// ---------------------------------------------------------------------------
__global__ __launch_bounds__(256) void gemm_fused_inline(
    const unsigned short* __restrict__ xb,
    const float* __restrict__ w,
    const int* __restrict__ labels,
    float* __restrict__ S, float* __restrict__ Lb) {
  int bid = blockIdx.x;
  int xcd = bid & 7;
  int slot = bid >> 3;
  int tn = xcd * 98 + (slot >> 3);
  int tm = slot & 7;
  if (tn >= NT_) return;
  int m0 = tm * 128, n0 = tn * 128;

  __shared__ unsigned short Ab[128 * 64];
  __shared__ unsigned short Bb[128 * 64];
  __shared__ float sqred[8][128];
  __shared__ float iwL[128];
  __shared__ int labT[128];
  int t = threadIdx.x;
  if (t < 128) labT[t] = labels[m0 + t];
  int lane = t & 63;
  int q = lane >> 4, l15 = lane & 15;
  int wave = t >> 6;
  int wm = (wave & 1) * 64, wn = (wave >> 1) * 64;
  f32x4 acc[4][4] = {};

  const unsigned short* gA[4];
  unsigned short* lA[4];
#pragma unroll
  for (int j = 0; j < 4; ++j) {
    int p = t + 256 * j;
    int m = p >> 3;
    int kc = (p & 7) ^ (m & 7);
    gA[j] = xb + (size_t)(m0 + m) * D_ + kc * 8;
    lA[j] = Ab + p * 8;
  }

  int cg = t & 31;
  int rp = t >> 5;
  int c0l = cg * 4;
  bool vok = (n0 + c0l + 3) < V_;
  const float* wbase = w + (size_t)rp * 8 * V_ + n0 + c0l;
  unsigned short* bdst[4];
#pragma unroll
  for (int cc = 0; cc < 4; ++cc) {
    int col = c0l + cc;
    bdst[cc] = &Bb[(col * 8 + (rp ^ (col & 7))) * 8];
  }
  float ssq[4] = {0.0f, 0.0f, 0.0f, 0.0f};

  for (int kt = 0; kt < D_; kt += 64) {
#pragma unroll
    for (int j = 0; j < 4; ++j) async_copy16(lA[j], gA[j] + kt);

    f32x4 row[8];
    if (vok) {
#pragma unroll
      for (int i = 0; i < 8; ++i)
        row[i] = *(const f32x4*)(wbase + (size_t)i * V_);
    } else {
#pragma unroll
      for (int i = 0; i < 8; ++i) row[i] = f32x4{0.0f, 0.0f, 0.0f, 0.0f};
    }
#pragma unroll
    for (int cc = 0; cc < 4; ++cc) {
      US8 pk;
#pragma unroll
      for (int i = 0; i < 8; ++i) {
        float v = row[i][cc];
        ssq[cc] += v * v;
        pk.h[i] = f2bf(v);
      }
      *(US8*)bdst[cc] = pk;
    }
    wbase += (size_t)64 * V_;

    __syncthreads();
    int h = l15 & 7;
#pragma unroll
    for (int s = 0; s < 2; ++s) {
      int kx = s * 4 + q;
      bf16x8 af[4], bfr[4];
#pragma unroll
      for (int ri = 0; ri < 4; ++ri) {
        int row_ = wm + ri * 16 + l15;
        af[ri] = *(const bf16x8*)&Ab[(row_ * 8 + (kx ^ h)) * 8];
      }
#pragma unroll
      for (int ci = 0; ci < 4; ++ci) {
        int row_ = wn + ci * 16 + l15;
        bfr[ci] = *(const bf16x8*)&Bb[(row_ * 8 + (kx ^ h)) * 8];
      }
#pragma unroll
      for (int ri = 0; ri < 4; ++ri)
#pragma unroll
        for (int ci = 0; ci < 4; ++ci)
          acc[ri][ci] = __builtin_amdgcn_mfma_f32_16x16x32_bf16(
              af[ri], bfr[ci], acc[ri][ci], 0, 0, 0);
    }
    __syncthreads();
  }

#pragma unroll
  for (int cc = 0; cc < 4; ++cc) sqred[rp][c0l + cc] = ssq[cc];
  __syncthreads();
  if (t < 128) {
    float tot = 0.0f;
#pragma unroll
    for (int p = 0; p < 8; ++p) tot += sqred[p][t];
    iwL[t] = ((n0 + t) < V_) ? 1.0f / fmaxf(sqrtf(tot), 1e-12f) : 0.0f;
  }
  __syncthreads();

  float iw[4]; int vcol[4];
#pragma unroll
  for (int ci = 0; ci < 4; ++ci) {
    int nl = wn + ci * 16 + l15;
    vcol[ci] = n0 + nl;
    iw[ci] = iwL[nl];
  }
#pragma unroll
  for (int ri = 0; ri < 4; ++ri) {
#pragma unroll
    for (int reg = 0; reg < 4; ++reg) {
      int ml = wm + ri * 16 + q * 4 + reg;
      int r = m0 + ml;
      int lab = labT[ml];
      float s = 0.0f;
#pragma unroll
      for (int ci = 0; ci < 4; ++ci) {
        float cv = acc[ri][ci][reg] * iw[ci];
        cv = fminf(fmaxf(cv, -1.0f + EPS_), 1.0f - EPS_);
        float logit = cv;
        if (vcol[ci] == lab) {
          logit = cv * COSM - sqrtf(fmaxf(1.0f - cv * cv, 0.0f)) * SINM;
          Lb[r] = logit;
        }
        s += (vcol[ci] < V_) ? __expf(logit) : 0.0f;
      }
      s += __shfl_xor(s, 1, 64);
      s += __shfl_xor(s, 2, 64);
      s += __shfl_xor(s, 4, 64);
      s += __shfl_xor(s, 8, 64);
      if (l15 == 0) atomicAdd(&S[r], s);
    }
  }
}

// ---------------------------------------------------------------------------
// Kernel 3: loss = mean(log(S) - label_logit)
// ---------------------------------------------------------------------------
__global__ void finalk(const float* __restrict__ S, const float* __restrict__ Lb,
                       float* __restrict__ out) {
  __shared__ float red[256];
  int t = threadIdx.x;
  float s = 0.0f;
  for (int i = t; i < B_; i += 256) s += logf(S[i]) - Lb[i];
  red[t] = s;
  __syncthreads();
  for (int o = 128; o > 0; o >>= 1) {
    if (t < o) red[t] += red[t + o];
    __syncthreads();
  }
  if (t == 0) out[0] = red[0] * (1.0f / B_);
}

// ---------------------------------------------------------------------------
extern "C" void kernel_launch(void* const* d_in, const int* in_sizes, int n_in,
                              void* d_out, int out_size, void* d_ws, size_t ws_size,
                              hipStream_t stream) {
  const float* x = (const float*)d_in[0];
  const float* w = (const float*)d_in[1];
  const int* labels = (const int*)d_in[2];
  float* out = (float*)d_out;
  char* ws = (char*)d_ws;
  // ws layout (16B-aligned):
  //   xb   @ 0        : 1024*512 bf16            = 1,048,576 B
  //   S    @ 1048576  : 1024 f32                 =     4,096 B
  //   Lb   @ 1052672  : 1024 f32                 =     4,096 B
  //   wssq @ 1056768  : 100096 f32               =   400,384 B
  //   wbT  @ 1457152  : 100096*512 bf16 (transp) = 102,498,304 B
  unsigned short* xb = (unsigned short*)ws;
  float* S    = (float*)(ws + 1048576ull);
  float* Lb   = (float*)(ws + 1052672ull);
  float* wssq = (float*)(ws + 1056768ull);
  unsigned short* wbT = (unsigned short*)(ws + 1457152ull);
  const size_t WS_NEED = 1457152ull + (size_t)NP_ * D_ * 2ull;

  x_prep<<<256, 256, 0, stream>>>(x, xb, S);
  if (ws_size >= WS_NEED) {
    w_prep<<<NP_ / WPC, 256, 0, stream>>>(w, wbT, wssq);
    gemm_fused_dma<<<3136, 512, 0, stream>>>(xb, wbT, wssq, labels, S, Lb);
  } else {
    gemm_fused_inline<<<6272, 256, 0, stream>>>(xb, w, labels, S, Lb);
  }
  finalk<<<1, 256, 0, stream>>>(S, Lb, out);
}